// Round 4
// baseline (956.417 us; speedup 1.0000x reference)
//
#include <hip/hip_runtime.h>
#include <stdint.h>
#include <stddef.h>

// ---------------------------------------------------------------------------
// DiffusionActionHead: fully fused 10-step DDPM sampler, bf16 MFMA.
//   B=32768, H=256, A=4, 10 inference steps.
// Pipeline (all on `stream`):
//   1. wprep_kernel  : repack 10 weight matrices -> bf16, MFMA-B-frag order
//                      (column remap: lane owns 2 CONSECUTIVE cols per group)
//   2. prep_kernel   : per-step temb-derived col-vectors tw1/tskip + scalars
//   3. noise_kernel  : JAX threefry2x32, PARTITIONABLE counter scheme
//   4. cond_kernel   : cond = features @ cond_w + cond_b  (bf16 out)
//   5. fused_kernel  : 10 steps x 9 K=256 GEMMs per 64-row tile.
//      ROUND 4 (post-mortem of round 3's 23.7% occupancy):
//        - r3: 2-ntile waves need >128 total regs -> AGPR overflow -> only
//          ONE 512-thr block/CU resident (8 waves = 23.7%), despite no spill.
//        - now: 1024-thread blocks, 16 waves, wave owns 32x32 (2rt x 2ct).
//          Accs resid[4]+work[4]=32 regs; arch VGPR ~90 << 128 cap -> no
//          AGPR overflow -> 16 waves/CU = 4 waves/SIMD = ~50% occupancy.
//        - weight layout (wlane = colg*8192) and barrier structure unchanged
//          from r3; per-block wts L2 traffic unchanged (512 blocks).
// ---------------------------------------------------------------------------

typedef __bf16 bf16_t;
typedef __bf16 bf16x8 __attribute__((ext_vector_type(8)));
typedef __bf16 bf16x4 __attribute__((ext_vector_type(4)));
typedef __bf16 bf16x2 __attribute__((ext_vector_type(2)));
typedef float  f32x4  __attribute__((ext_vector_type(4)));
typedef float  f32x2  __attribute__((ext_vector_type(2)));

constexpr int KP    = 264;   // LDS row stride in bf16 elems (256 + 8 pad)
constexpr int MTILE = 64;    // rows per workgroup

// ---------------- exact-erf GELU (Abramowitz-Stegun 7.1.26, |err|<1.5e-7) ---
__device__ __forceinline__ float gelu_f(float x) {
  float z  = 0.70710678f * x;
  float az = fabsf(z);
  float t  = __builtin_amdgcn_rcpf(fmaf(0.3275911f, az, 1.0f));
  float e  = __expf(-az * az);
  float p  = fmaf(1.061405429f, t, -1.453152027f);
  p = fmaf(p, t, 1.421413741f);
  p = fmaf(p, t, -0.284496736f);
  p = fmaf(p, t, 0.254829592f);
  float er = fmaf(-(p * t), e, 1.0f);   // erf(|z|)
  er = copysignf(er, z);
  return 0.5f * x * (1.0f + er);
}

// ---------------- JAX threefry2x32 (20 rounds) ------------------------------
#define TFR(a) x0 += x1; x1 = (x1 << (a)) | (x1 >> (32 - (a))); x1 ^= x0;
__device__ __forceinline__ void tf2(uint32_t k0, uint32_t k1,
                                    uint32_t x0, uint32_t x1,
                                    uint32_t& o0, uint32_t& o1) {
  uint32_t k2 = k0 ^ k1 ^ 0x1BD11BDAu;
  x0 += k0; x1 += k1;
  TFR(13) TFR(15) TFR(26) TFR(6)
  x0 += k1; x1 += k2 + 1u;
  TFR(17) TFR(29) TFR(16) TFR(24)
  x0 += k2; x1 += k0 + 2u;
  TFR(13) TFR(15) TFR(26) TFR(6)
  x0 += k0; x1 += k1 + 3u;
  TFR(17) TFR(29) TFR(16) TFR(24)
  x0 += k1; x1 += k2 + 4u;
  TFR(13) TFR(15) TFR(26) TFR(6)
  x0 += k2; x1 += k0 + 5u;
  o0 = x0; o1 = x1;
}
#undef TFR

// uniform bits -> N(0,1) exactly like jax.random.normal (XLA erfinv poly)
__device__ __forceinline__ float nrm_from_bits(uint32_t bits) {
  float f = __uint_as_float((bits >> 9) | 0x3f800000u) - 1.0f;  // [0,1)
  const float lo = -0.99999994f;                                 // nextafter(-1,0)
  float u = fmaxf(lo, __fadd_rn(__fmul_rn(f, 2.0f), lo));        // (hi-lo)==2.0f in f32
  float w = -log1pf(-__fmul_rn(u, u));
  float p;
  if (w < 5.0f) {
    float ww = w - 2.5f;
    p = 2.81022636e-08f;
    p = fmaf(p, ww, 3.43273939e-07f);
    p = fmaf(p, ww, -3.5233877e-06f);
    p = fmaf(p, ww, -4.39150654e-06f);
    p = fmaf(p, ww, 0.00021858087f);
    p = fmaf(p, ww, -0.00125372503f);
    p = fmaf(p, ww, -0.00417768164f);
    p = fmaf(p, ww, 0.246640727f);
    p = fmaf(p, ww, 1.50140941f);
  } else {
    float ww = sqrtf(w) - 3.0f;
    p = -0.000200214257f;
    p = fmaf(p, ww, 0.000100950558f);
    p = fmaf(p, ww, 0.00134934322f);
    p = fmaf(p, ww, -0.00367342844f);
    p = fmaf(p, ww, 0.00573950773f);
    p = fmaf(p, ww, -0.0076224613f);
    p = fmaf(p, ww, 0.00943887047f);
    p = fmaf(p, ww, 1.00167406f);
    p = fmaf(p, ww, 2.83297682f);
  }
  return 1.41421354f * (p * u);   // sqrt(2) * erfinv(u)
}

// ---------------- 64x64 MFMA tile (4 ntiles/wave, cond_kernel) -------------
__device__ __forceinline__ void mm_tile(const bf16_t* __restrict__ A,
                                        const bf16_t* __restrict__ Wp,
                                        f32x4 acc[16]) {
  #pragma unroll
  for (int i = 0; i < 16; ++i) acc[i] = f32x4{0.f, 0.f, 0.f, 0.f};
  #pragma unroll 2
  for (int kc = 0; kc < 8; ++kc) {
    bf16x8 a[4], b[4];
    #pragma unroll
    for (int rt = 0; rt < 4; ++rt)
      a[rt] = *(const bf16x8*)(A + rt * 16 * KP + kc * 32);
    #pragma unroll
    for (int ct = 0; ct < 4; ++ct)
      b[ct] = *(const bf16x8*)(Wp + ct * 4096 + kc * 512);
    #pragma unroll
    for (int rt = 0; rt < 4; ++rt)
      #pragma unroll
      for (int ct = 0; ct < 4; ++ct)
        acc[rt * 4 + ct] =
            __builtin_amdgcn_mfma_f32_16x16x32_bf16(a[rt], b[ct], acc[rt * 4 + ct], 0, 0, 0);
  }
}

// ---------------- 32x32 MFMA tile (2rt x 2ct, fused_kernel) ----------------
// A: row-major LDS, stride KP, pre-offset by (rbase+l16)*KP + quad*8.
// Wp: pre-offset colg*8192 + lane*8; b[ct] at ct*4096 + kc*512.
__device__ __forceinline__ void mm_tile22(const bf16_t* __restrict__ A,
                                          const bf16_t* __restrict__ Wp,
                                          f32x4 acc[4]) {
  #pragma unroll
  for (int i = 0; i < 4; ++i) acc[i] = f32x4{0.f, 0.f, 0.f, 0.f};
  #pragma unroll 2
  for (int kc = 0; kc < 8; ++kc) {
    bf16x8 a[2], b[2];
    #pragma unroll
    for (int rt = 0; rt < 2; ++rt)
      a[rt] = *(const bf16x8*)(A + rt * 16 * KP + kc * 32);
    #pragma unroll
    for (int ct = 0; ct < 2; ++ct)
      b[ct] = *(const bf16x8*)(Wp + ct * 4096 + kc * 512);
    #pragma unroll
    for (int rt = 0; rt < 2; ++rt)
      #pragma unroll
      for (int ct = 0; ct < 2; ++ct)
        acc[rt * 2 + ct] =
            __builtin_amdgcn_mfma_f32_16x16x32_bf16(a[rt], b[ct], acc[rt * 2 + ct], 0, 0, 0);
  }
}

// ---------------- kernel 1: weight repack ----------------------------------
// dst element e = [m][nt][kc][lane][j]; value = src_m[k*256 + n],
// COLUMN REMAP: n = (nt>>1)*32 + (lane&15)*2 + (nt&1)
// -> fused col-group g (ntiles 2g,2g+1): lane cols = g*32 + l16*2 + {0,1}
// -> cond wave w (ntiles 4w..4w+3): cols w*64 + (ct>>1)*32 + l16*2 + (ct&1)
__global__ void wprep_kernel(const float* __restrict__ condw,
                             const float* __restrict__ w1,
                             const float* __restrict__ skw,
                             const float* __restrict__ w2,
                             const float* __restrict__ bw1,
                             const float* __restrict__ bw2,
                             bf16_t* __restrict__ wts) {
  int e = blockIdx.x * 256 + threadIdx.x;
  int m = e >> 16;
  int r = e & 65535;
  int nt = r >> 12, kc = (r >> 9) & 7, lane = (r >> 3) & 63, j = r & 7;
  int n = (nt >> 1) * 32 + (lane & 15) * 2 + (nt & 1);
  int k = kc * 32 + (lane >> 4) * 8 + j;
  const float* src;
  if      (m == 0) src = condw;
  else if (m == 1) src = w1;                    // blk0_w1 rows 0..255 (cond part)
  else if (m == 2) src = skw;                   // blk0_skip_w rows 0..255
  else if (m == 3) src = w2;                    // blk0_w2
  else if (m <= 6) src = bw1 + (m - 4) * 65536; // blks_w1[i]
  else             src = bw2 + (m - 7) * 65536; // blks_w2[i]
  wts[e] = (bf16_t)src[k * 256 + n];
}

// ---------------- kernel 2: per-step vectors + scalars ---------------------
__global__ void prep_kernel(const float* __restrict__ time_w,
                            const float* __restrict__ time_b,
                            const float* __restrict__ w1,
                            const float* __restrict__ b1,
                            const float* __restrict__ skw,
                            const float* __restrict__ skb,
                            float* __restrict__ tvecs,
                            float* __restrict__ stepsc) {
  int s = blockIdx.x;          // 0..9, t = 90 - 10*s
  int j = threadIdx.x;         // 0..255
  int t = 90 - s * 10;
  float tval = (float)t;
  __shared__ float emb[256];
  __shared__ float temb[256];
  if (j < 128) {
    float freq = expf((float)j * -0.07252236513366287f);  // -ln(1e4)/127
    float e = tval * freq;
    emb[j] = sinf(e);
    emb[j + 128] = cosf(e);
  }
  __syncthreads();
  float a = time_b[j];
  for (int k = 0; k < 256; ++k) a = fmaf(emb[k], time_w[k * 256 + j], a);
  temb[j] = gelu_f(a);
  __syncthreads();
  float v1 = b1[j], v2 = skb[j];
  for (int k = 0; k < 256; ++k) {
    float tk = temb[k];
    v1 = fmaf(tk, w1[(256 + k) * 256 + j], v1);    // blk0_w1 rows 256..511
    v2 = fmaf(tk, skw[(256 + k) * 256 + j], v2);   // blk0_skip_w rows 256..511
  }
  tvecs[s * 512 + j] = v1;         // tw1 (includes b1)
  tvecs[s * 512 + 256 + j] = v2;   // tskip (includes skip_b)
  if (j == 0) {
    float step = (0.02f - 1e-4f) / 99.0f;
    float acp = 1.0f, beta = 0.0f;
    for (int i = 0; i <= t; ++i) {
      beta = fmaf((float)i, step, 1e-4f);
      acp *= (1.0f - beta);
    }
    stepsc[s * 4 + 0] = 1.0f / sqrtf(1.0f - beta);   // 1/sqrt(alpha)
    stepsc[s * 4 + 1] = beta / sqrtf(1.0f - acp);    // b/sqrt(1-acp)
    stepsc[s * 4 + 2] = (t > 0) ? sqrtf(beta) : 0.0f;
    stepsc[s * 4 + 3] = 0.0f;
  }
}

// ---------------- kernel 3: x0 + noises via PARTITIONABLE threefry ---------
__global__ void noise_kernel(float* __restrict__ xout, float* __restrict__ nout, int nb) {
  int gid = blockIdx.x * 256 + threadIdx.x;
  int nx = nb * 4;     // 131072 x0 elements
  int nn = nb * 40;    // 1310720 noise elements
  uint32_t k0, k1, o0, o1;
  if (gid < nx) {
    tf2(0u, 42u, 0u, 999u, k0, k1);                 // fold_in(key(42), 999)
    tf2(k0, k1, 0u, (uint32_t)gid, o0, o1);
    xout[gid] = nrm_from_bits(o0 ^ o1);
  } else if (gid < nx + nn) {
    int i = gid - nx;
    tf2(0u, 42u, 0u, 7u, k0, k1);                   // fold_in(key(42), 7)
    tf2(k0, k1, 0u, (uint32_t)i, o0, o1);
    nout[i] = nrm_from_bits(o0 ^ o1);
  }
}

// ---------------- kernel 4: cond = features @ cond_w + cond_b --------------
__global__ __launch_bounds__(256, 2) void cond_kernel(
    const float* __restrict__ feat, const bf16_t* __restrict__ wts,
    const float* __restrict__ condb, bf16_t* __restrict__ condg) {
  __shared__ __align__(16) bf16_t la[MTILE * KP];
  const int tid = threadIdx.x;
  const int wave = tid >> 6, lane = tid & 63, quad = lane >> 4, l16 = lane & 15;
  const int rowbase = blockIdx.x * MTILE;
  for (int it = 0; it < 16; ++it) {
    int e = (it * 256 + tid) * 4;
    int rr = e >> 8, c = e & 255;
    f32x4 v = *(const f32x4*)(feat + (size_t)(rowbase + rr) * 256 + c);
    bf16x4 bv;
    bv[0] = (bf16_t)v[0]; bv[1] = (bf16_t)v[1];
    bv[2] = (bf16_t)v[2]; bv[3] = (bf16_t)v[3];
    *(bf16x4*)(la + rr * KP + c) = bv;
  }
  __syncthreads();
  f32x4 acc[16];
  mm_tile(la + l16 * KP + quad * 8, wts + wave * 16384 + lane * 8, acc);
  const int c0 = wave * 64 + l16 * 2;            // ct 0,1 -> c0, ct 2,3 -> c0+32
  f32x2 b0 = *(const f32x2*)(condb + c0);
  f32x2 b1 = *(const f32x2*)(condb + c0 + 32);
  #pragma unroll
  for (int rt = 0; rt < 4; ++rt)
    #pragma unroll
    for (int r = 0; r < 4; ++r) {
      int row = rt * 16 + quad * 4 + r;
      bf16x2 p0, p1;
      p0[0] = (bf16_t)(acc[rt * 4 + 0][r] + b0[0]);
      p0[1] = (bf16_t)(acc[rt * 4 + 1][r] + b0[1]);
      p1[0] = (bf16_t)(acc[rt * 4 + 2][r] + b1[0]);
      p1[1] = (bf16_t)(acc[rt * 4 + 3][r] + b1[1]);
      *(bf16x2*)(condg + (size_t)(rowbase + row) * 256 + c0) = p0;
      *(bf16x2*)(condg + (size_t)(rowbase + row) * 256 + c0 + 32) = p1;
    }
}

// ---------------- kernel 5: fused 10-step sampler (1024 thr / 16 waves) ----
// wave = rowh*8 + colg: rowh in {0,1} (32-row half), colg in [0,8) (32 cols)
__global__ __launch_bounds__(1024, 2) void fused_kernel(
    const bf16_t* __restrict__ condg, const bf16_t* __restrict__ wts,
    const float* __restrict__ tvecs, const float* __restrict__ stepsc,
    const float* __restrict__ x0w, const float* __restrict__ noises,
    const float* __restrict__ w1bot, const float* __restrict__ skipbot,
    const float* __restrict__ b2v, const float* __restrict__ blksb1,
    const float* __restrict__ blksb2, const float* __restrict__ finalw,
    const float* __restrict__ finalb, float* __restrict__ out, int nb) {
  __shared__ __align__(16) bf16_t lcond[MTILE * KP];
  __shared__ __align__(16) bf16_t lact[MTILE * KP];
  __shared__ __align__(16) float  lx[MTILE * 4];
  __shared__ __align__(16) float  lfw[1024];
  const int tid = threadIdx.x;
  const int wave = tid >> 6, lane = tid & 63, quad = lane >> 4, l16 = lane & 15;
  const int rowh = wave >> 3;          // 0..1: 32-row half
  const int colg = wave & 7;           // 0..7: 32-col group
  const int rbase = rowh * 32;
  const int rowbase = blockIdx.x * MTILE;

  // stage cond tile (persists all 10 steps) + x0 + final_w
  {
    int rr = tid >> 4, c = (tid & 15) * 16;
    const bf16_t* src = condg + (size_t)(rowbase + rr) * 256 + c;
    bf16_t* dst = lcond + rr * KP + c;
    *(bf16x8*)(dst)     = *(const bf16x8*)(src);
    *(bf16x8*)(dst + 8) = *(const bf16x8*)(src + 8);
  }
  if (tid < 256) lx[tid] = x0w[rowbase * 4 + tid];
  lfw[tid] = finalw[tid];
  __syncthreads();

  const bf16_t* Acond = lcond + (rbase + l16) * KP + quad * 8;
  const bf16_t* Aact  = lact + (rbase + l16) * KP + quad * 8;
  const int colw = colg * 32 + l16 * 2;          // 2 consecutive cols/lane
  const int wlane = colg * 8192 + lane * 8;
  f32x4 resid[4], work[4];

  // pack lane's 2 consecutive cols -> one ds_write_b32 per (rt,r)
  auto write_act = [&]() {
    #pragma unroll
    for (int rt = 0; rt < 2; ++rt)
      #pragma unroll
      for (int r = 0; r < 4; ++r) {
        bf16x2 pv;
        pv[0] = (bf16_t)work[rt * 2 + 0][r];
        pv[1] = (bf16_t)work[rt * 2 + 1][r];
        *(bf16x2*)(lact + (rbase + rt * 16 + quad * 4 + r) * KP + colw) = pv;
      }
  };
  // K=516-factorized epilogue, skip path (no gelu), in-place on resid
  auto epi_bot_res = [&](const float* tvec, const float* bot) {
    f32x2 tc = *(const f32x2*)(tvec + colw);
    f32x2 s0 = *(const f32x2*)(bot + colw);
    f32x2 s1 = *(const f32x2*)(bot + 256 + colw);
    f32x2 s2 = *(const f32x2*)(bot + 512 + colw);
    f32x2 s3 = *(const f32x2*)(bot + 768 + colw);
    #pragma unroll
    for (int rt = 0; rt < 2; ++rt)
      #pragma unroll
      for (int r = 0; r < 4; ++r) {
        f32x4 xv = *(const f32x4*)(lx + (rbase + rt * 16 + quad * 4 + r) * 4);
        #pragma unroll
        for (int ct = 0; ct < 2; ++ct) {
          int i = rt * 2 + ct;
          float v = resid[i][r] + tc[ct];
          v = fmaf(xv[0], s0[ct], v);
          v = fmaf(xv[1], s1[ct], v);
          v = fmaf(xv[2], s2[ct], v);
          v = fmaf(xv[3], s3[ct], v);
          resid[i][r] = v;
        }
      }
  };
  // K=516-factorized epilogue, y1 path (gelu), in-place on work
  auto epi_bot_gelu = [&](const float* tvec, const float* bot) {
    f32x2 tc = *(const f32x2*)(tvec + colw);
    f32x2 s0 = *(const f32x2*)(bot + colw);
    f32x2 s1 = *(const f32x2*)(bot + 256 + colw);
    f32x2 s2 = *(const f32x2*)(bot + 512 + colw);
    f32x2 s3 = *(const f32x2*)(bot + 768 + colw);
    #pragma unroll
    for (int rt = 0; rt < 2; ++rt)
      #pragma unroll
      for (int r = 0; r < 4; ++r) {
        f32x4 xv = *(const f32x4*)(lx + (rbase + rt * 16 + quad * 4 + r) * 4);
        #pragma unroll
        for (int ct = 0; ct < 2; ++ct) {
          int i = rt * 2 + ct;
          float v = work[i][r] + tc[ct];
          v = fmaf(xv[0], s0[ct], v);
          v = fmaf(xv[1], s1[ct], v);
          v = fmaf(xv[2], s2[ct], v);
          v = fmaf(xv[3], s3[ct], v);
          work[i][r] = gelu_f(v);
        }
      }
  };
  auto epi_gelu = [&](const float* bias) {
    f32x2 bc = *(const f32x2*)(bias + colw);
    #pragma unroll
    for (int i = 0; i < 4; ++i)
      #pragma unroll
      for (int r = 0; r < 4; ++r) work[i][r] = gelu_f(work[i][r] + bc[i & 1]);
  };
  auto epi_gelu_res = [&](const float* bias) {
    f32x2 bc = *(const f32x2*)(bias + colw);
    #pragma unroll
    for (int i = 0; i < 4; ++i)
      #pragma unroll
      for (int r = 0; r < 4; ++r) {
        float v = gelu_f(work[i][r] + bc[i & 1]) + resid[i][r];
        resid[i][r] = v;
        work[i][r] = v;
      }
  };

  for (int s = 0; s < 10; ++s) {
    const float* tw  = tvecs + s * 512;
    const float* tsk = tvecs + s * 512 + 256;
    // skip = cond @ Wskip_top + x @ Wskip_bot + tskip   -> resid (f32 regs)
    mm_tile22(Acond, wts + 2 * 65536 + wlane, resid);
    epi_bot_res(tsk, skipbot);
    // y1 = gelu(cond @ W1_top + x @ W1_bot + tw1)       -> lact
    mm_tile22(Acond, wts + 1 * 65536 + wlane, work);
    epi_bot_gelu(tw, w1bot);
    write_act();          // lact free: prev step's readers done at step-end sync
    __syncthreads();      // write -> read
    // h = gelu(y1 @ W2 + b2) + skip                     -> resid + lact
    mm_tile22(Aact, wts + 3 * 65536 + wlane, work);
    __syncthreads();      // reads done (epi is reg-only, write comes after)
    epi_gelu_res(b2v);
    write_act();
    __syncthreads();      // write -> read
    // 3 residual blocks
    for (int blk = 0; blk < 3; ++blk) {
      mm_tile22(Aact, wts + (4 + blk) * 65536 + wlane, work);
      __syncthreads();    // reads done
      epi_gelu(blksb1 + blk * 256);
      write_act();
      __syncthreads();    // write -> read
      mm_tile22(Aact, wts + (7 + blk) * 65536 + wlane, work);
      __syncthreads();    // reads done
      epi_gelu_res(blksb2 + blk * 256);
      write_act();
      __syncthreads();    // write -> read
    }
    // pred = h @ final_w + final_b; x-update (one thread per (row, action))
    if (tid < 256) {
      int prow = tid >> 2, pc = tid & 3;
      const bf16_t* hp = lact + prow * KP;
      float a0 = 0.f, a1 = 0.f, a2 = 0.f, a3 = 0.f;    // 4 chains: break dep
      #pragma unroll 2
      for (int k = 0; k < 256; k += 32) {
        #pragma unroll
        for (int q = 0; q < 4; ++q) {
          bf16x8 hv = *(const bf16x8*)(hp + k + q * 8);
          float* ap = (q == 0) ? &a0 : (q == 1) ? &a1 : (q == 2) ? &a2 : &a3;
          #pragma unroll
          for (int j = 0; j < 8; ++j)
            *ap = fmaf((float)hv[j], lfw[(k + q * 8 + j) * 4 + pc], *ap);
        }
      }
      float accp = finalb[pc] + ((a0 + a1) + (a2 + a3));
      f32x4 sc = *(const f32x4*)(stepsc + s * 4);
      float xv = lx[tid];
      xv = (xv - sc[1] * accp) * sc[0];
      xv = fmaf(sc[2], noises[(size_t)s * nb * 4 + rowbase * 4 + tid], xv);
      lx[tid] = xv;   // own slot; cross-thread reads only after barrier below
    }
    __syncthreads();      // step-end: lx visible + lact read-done
  }
  if (tid < 256) {
    float xf = lx[tid];
    xf = fminf(1.0f, fmaxf(-1.0f, xf));
    out[rowbase * 4 + tid] = xf;
  }
}

// ---------------------------------------------------------------------------
extern "C" void kernel_launch(void* const* d_in, const int* in_sizes, int n_in,
                              void* d_out, int out_size, void* d_ws, size_t ws_size,
                              hipStream_t stream) {
  (void)n_in; (void)out_size; (void)ws_size;
  const float* features    = (const float*)d_in[0];
  const float* cond_w      = (const float*)d_in[1];
  const float* cond_b      = (const float*)d_in[2];
  const float* time_w      = (const float*)d_in[3];
  const float* time_b      = (const float*)d_in[4];
  const float* blk0_w1     = (const float*)d_in[5];
  const float* blk0_b1     = (const float*)d_in[6];
  const float* blk0_w2     = (const float*)d_in[7];
  const float* blk0_b2     = (const float*)d_in[8];
  const float* blk0_skip_w = (const float*)d_in[9];
  const float* blk0_skip_b = (const float*)d_in[10];
  const float* blks_w1     = (const float*)d_in[11];
  const float* blks_b1     = (const float*)d_in[12];
  const float* blks_w2     = (const float*)d_in[13];
  const float* blks_b2     = (const float*)d_in[14];
  const float* final_w     = (const float*)d_in[15];
  const float* final_b     = (const float*)d_in[16];

  const int nb = in_sizes[0] / 256;   // batch (32768)

  // workspace layout (bytes, 256-aligned)
  char* ws = (char*)d_ws;
  bf16_t* wts    = (bf16_t*)(ws + 0);        // 10 * 65536 bf16 = 1,310,720 B
  float*  tvecs  = (float*)(ws + 1310720);   // 10 * 512 f32    = 20,480 B
  float*  stepsc = (float*)(ws + 1331200);   // 10 * 4 f32      (pad to 256)
  float*  x0w    = (float*)(ws + 1331456);   // nb*4 f32        = 524,288 B
  float*  noisew = (float*)(ws + 1855744);   // 10*nb*4 f32     = 5,242,880 B
  bf16_t* condw  = (bf16_t*)(ws + 7098624);  // nb*256 bf16     = 16,777,216 B

  wprep_kernel<<<2560, 256, 0, stream>>>(cond_w, blk0_w1, blk0_skip_w, blk0_w2,
                                         blks_w1, blks_w2, wts);
  prep_kernel<<<10, 256, 0, stream>>>(time_w, time_b, blk0_w1, blk0_b1,
                                      blk0_skip_w, blk0_skip_b, tvecs, stepsc);
  noise_kernel<<<(nb * 44 + 255) / 256, 256, 0, stream>>>(x0w, noisew, nb);
  cond_kernel<<<nb / MTILE, 256, 0, stream>>>(features, wts, cond_b, condw);
  fused_kernel<<<nb / MTILE, 1024, 0, stream>>>(
      condw, wts, tvecs, stepsc, x0w, noisew,
      blk0_w1 + 512 * 256, blk0_skip_w + 512 * 256, blk0_b2,
      blks_b1, blks_b2, final_w, final_b, (float*)d_out, nb);
}

// Round 5
// 790.035 us; speedup vs baseline: 1.2106x; 1.2106x over previous
//
#include <hip/hip_runtime.h>
#include <stdint.h>
#include <stddef.h>

// ---------------------------------------------------------------------------
// DiffusionActionHead: fully fused 10-step DDPM sampler, bf16 MFMA.
//   B=32768, H=256, A=4, 10 inference steps.
// Pipeline (all on `stream`):
//   1. wprep_kernel  : repack 10 weight matrices -> bf16, MFMA-B-frag order
//   2. prep_kernel   : per-step temb-derived col-vectors tw1/tskip + scalars
//   3. noise_kernel  : JAX threefry2x32, PARTITIONABLE counter scheme
//   4. cond_kernel   : cond = features @ cond_w + cond_b  (bf16 out)
//   5. fused_kernel  : 10 steps x 9 K=256 GEMMs per 64-row tile.
//      ROUND 5 (post-mortem r4: occupancy 2x bought nothing -> kernel is
//      serialization-bound + VALU-heavy, not latency-bound; r3=833us base):
//        - dual GEMM skip+y1: both read lcond -> one A-fragment pass feeds
//          both B's; merged epilogue shares the lx loads.
//        - double-buffered lact0/lact1 -> 9 barriers/step (was 16).
//          Dep-audited: each buffer's readers finish >=1 barrier before
//          its next writer, incl. cross-step.
//        - packed f32x2 epilogues + gelu2 (v_pk_fma_f32 path): per-element
//          math bit-identical, ~35% fewer epilogue VALU instructions.
//        - LDS 109.6KB -> 1 block/CU regardless of VGPR, so launch_bounds
//          (512,1) = 256-reg cap: no spill (r2/r4 lesson: cap=131072/(bs*a2)).
//        - KP 264->272 (bank-conflict probe; SQ_LDS_BANK_CONFLICT decides).
// ---------------------------------------------------------------------------

typedef __bf16 bf16_t;
typedef __bf16 bf16x8 __attribute__((ext_vector_type(8)));
typedef __bf16 bf16x4 __attribute__((ext_vector_type(4)));
typedef __bf16 bf16x2 __attribute__((ext_vector_type(2)));
typedef float  f32x4  __attribute__((ext_vector_type(4)));
typedef float  f32x2  __attribute__((ext_vector_type(2)));
typedef uint32_t u32x2 __attribute__((ext_vector_type(2)));

constexpr int KP    = 272;   // LDS row stride in bf16 elems (256 + 16 pad)
constexpr int MTILE = 64;    // rows per workgroup

// ---------------- packed f32x2 helpers -------------------------------------
__device__ __forceinline__ f32x2 bc2(float v) { return f32x2{v, v}; }
__device__ __forceinline__ f32x2 fma2(f32x2 a, f32x2 b, f32x2 c) {
#if __has_builtin(__builtin_elementwise_fma)
  return __builtin_elementwise_fma(a, b, c);
#else
  return f32x2{fmaf(a[0], b[0], c[0]), fmaf(a[1], b[1], c[1])};
#endif
}
__device__ __forceinline__ f32x2 abs2(f32x2 x) {
#if __has_builtin(__builtin_elementwise_abs)
  return __builtin_elementwise_abs(x);
#else
  return f32x2{fabsf(x[0]), fabsf(x[1])};
#endif
}

// ---------------- exact-erf GELU (A&S 7.1.26), scalar and packed ------------
__device__ __forceinline__ float gelu_f(float x) {
  float z  = 0.70710678f * x;
  float az = fabsf(z);
  float t  = __builtin_amdgcn_rcpf(fmaf(0.3275911f, az, 1.0f));
  float e  = __expf(-az * az);
  float p  = fmaf(1.061405429f, t, -1.453152027f);
  p = fmaf(p, t, 1.421413741f);
  p = fmaf(p, t, -0.284496736f);
  p = fmaf(p, t, 0.254829592f);
  float er = fmaf(-(p * t), e, 1.0f);   // erf(|z|)
  er = copysignf(er, z);
  return 0.5f * x * (1.0f + er);
}
// per-half op sequence identical to gelu_f (fma2==fmaf per lane)
__device__ __forceinline__ f32x2 gelu2(f32x2 x) {
  f32x2 z  = bc2(0.70710678f) * x;
  f32x2 az = abs2(z);
  f32x2 d  = fma2(bc2(0.3275911f), az, bc2(1.0f));
  f32x2 t; t[0] = __builtin_amdgcn_rcpf(d[0]); t[1] = __builtin_amdgcn_rcpf(d[1]);
  f32x2 naz = -az * az;
  f32x2 e; e[0] = __expf(naz[0]); e[1] = __expf(naz[1]);
  f32x2 p  = fma2(bc2(1.061405429f), t, bc2(-1.453152027f));
  p = fma2(p, t, bc2(1.421413741f));
  p = fma2(p, t, bc2(-0.284496736f));
  p = fma2(p, t, bc2(0.254829592f));
  f32x2 q  = p * t;
  f32x2 er = fma2(-q, e, bc2(1.0f));
  er[0] = copysignf(er[0], z[0]);
  er[1] = copysignf(er[1], z[1]);
  return (bc2(0.5f) * x) * (bc2(1.0f) + er);
}

// ---------------- JAX threefry2x32 (20 rounds) ------------------------------
#define TFR(a) x0 += x1; x1 = (x1 << (a)) | (x1 >> (32 - (a))); x1 ^= x0;
__device__ __forceinline__ void tf2(uint32_t k0, uint32_t k1,
                                    uint32_t x0, uint32_t x1,
                                    uint32_t& o0, uint32_t& o1) {
  uint32_t k2 = k0 ^ k1 ^ 0x1BD11BDAu;
  x0 += k0; x1 += k1;
  TFR(13) TFR(15) TFR(26) TFR(6)
  x0 += k1; x1 += k2 + 1u;
  TFR(17) TFR(29) TFR(16) TFR(24)
  x0 += k2; x1 += k0 + 2u;
  TFR(13) TFR(15) TFR(26) TFR(6)
  x0 += k0; x1 += k1 + 3u;
  TFR(17) TFR(29) TFR(16) TFR(24)
  x0 += k1; x1 += k2 + 4u;
  TFR(13) TFR(15) TFR(26) TFR(6)
  x0 += k2; x1 += k0 + 5u;
  o0 = x0; o1 = x1;
}
#undef TFR

// uniform bits -> N(0,1) exactly like jax.random.normal (XLA erfinv poly)
__device__ __forceinline__ float nrm_from_bits(uint32_t bits) {
  float f = __uint_as_float((bits >> 9) | 0x3f800000u) - 1.0f;  // [0,1)
  const float lo = -0.99999994f;                                 // nextafter(-1,0)
  float u = fmaxf(lo, __fadd_rn(__fmul_rn(f, 2.0f), lo));        // (hi-lo)==2.0f in f32
  float w = -log1pf(-__fmul_rn(u, u));
  float p;
  if (w < 5.0f) {
    float ww = w - 2.5f;
    p = 2.81022636e-08f;
    p = fmaf(p, ww, 3.43273939e-07f);
    p = fmaf(p, ww, -3.5233877e-06f);
    p = fmaf(p, ww, -4.39150654e-06f);
    p = fmaf(p, ww, 0.00021858087f);
    p = fmaf(p, ww, -0.00125372503f);
    p = fmaf(p, ww, -0.00417768164f);
    p = fmaf(p, ww, 0.246640727f);
    p = fmaf(p, ww, 1.50140941f);
  } else {
    float ww = sqrtf(w) - 3.0f;
    p = -0.000200214257f;
    p = fmaf(p, ww, 0.000100950558f);
    p = fmaf(p, ww, 0.00134934322f);
    p = fmaf(p, ww, -0.00367342844f);
    p = fmaf(p, ww, 0.00573950773f);
    p = fmaf(p, ww, -0.0076224613f);
    p = fmaf(p, ww, 0.00943887047f);
    p = fmaf(p, ww, 1.00167406f);
    p = fmaf(p, ww, 2.83297682f);
  }
  return 1.41421354f * (p * u);   // sqrt(2) * erfinv(u)
}

// ---------------- 64x64 MFMA tile (4 ntiles/wave, cond_kernel) -------------
__device__ __forceinline__ void mm_tile(const bf16_t* __restrict__ A,
                                        const bf16_t* __restrict__ Wp,
                                        f32x4 acc[16]) {
  #pragma unroll
  for (int i = 0; i < 16; ++i) acc[i] = f32x4{0.f, 0.f, 0.f, 0.f};
  #pragma unroll 2
  for (int kc = 0; kc < 8; ++kc) {
    bf16x8 a[4], b[4];
    #pragma unroll
    for (int rt = 0; rt < 4; ++rt)
      a[rt] = *(const bf16x8*)(A + rt * 16 * KP + kc * 32);
    #pragma unroll
    for (int ct = 0; ct < 4; ++ct)
      b[ct] = *(const bf16x8*)(Wp + ct * 4096 + kc * 512);
    #pragma unroll
    for (int rt = 0; rt < 4; ++rt)
      #pragma unroll
      for (int ct = 0; ct < 4; ++ct)
        acc[rt * 4 + ct] =
            __builtin_amdgcn_mfma_f32_16x16x32_bf16(a[rt], b[ct], acc[rt * 4 + ct], 0, 0, 0);
  }
}

// ---------------- 64x32 MFMA tile (2 ntiles/wave, fused_kernel) ------------
__device__ __forceinline__ void mm_tile2(const bf16_t* __restrict__ A,
                                         const bf16_t* __restrict__ Wp,
                                         f32x4 acc[8]) {
  #pragma unroll
  for (int i = 0; i < 8; ++i) acc[i] = f32x4{0.f, 0.f, 0.f, 0.f};
  #pragma unroll 2
  for (int kc = 0; kc < 8; ++kc) {
    bf16x8 a[4], b[2];
    #pragma unroll
    for (int rt = 0; rt < 4; ++rt)
      a[rt] = *(const bf16x8*)(A + rt * 16 * KP + kc * 32);
    #pragma unroll
    for (int ct = 0; ct < 2; ++ct)
      b[ct] = *(const bf16x8*)(Wp + ct * 4096 + kc * 512);
    #pragma unroll
    for (int rt = 0; rt < 4; ++rt)
      #pragma unroll
      for (int ct = 0; ct < 2; ++ct)
        acc[rt * 2 + ct] =
            __builtin_amdgcn_mfma_f32_16x16x32_bf16(a[rt], b[ct], acc[rt * 2 + ct], 0, 0, 0);
  }
}

// Dual: one A pass (lcond) feeds TWO B's -> skip (acc1) + y1 (acc2)
__device__ __forceinline__ void mm_tile2_dual(const bf16_t* __restrict__ A,
                                              const bf16_t* __restrict__ W1,
                                              const bf16_t* __restrict__ W2,
                                              f32x4 acc1[8], f32x4 acc2[8]) {
  #pragma unroll
  for (int i = 0; i < 8; ++i) {
    acc1[i] = f32x4{0.f, 0.f, 0.f, 0.f};
    acc2[i] = f32x4{0.f, 0.f, 0.f, 0.f};
  }
  #pragma unroll 2
  for (int kc = 0; kc < 8; ++kc) {
    bf16x8 a[4];
    #pragma unroll
    for (int rt = 0; rt < 4; ++rt)
      a[rt] = *(const bf16x8*)(A + rt * 16 * KP + kc * 32);
    #pragma unroll
    for (int ct = 0; ct < 2; ++ct) {
      bf16x8 b = *(const bf16x8*)(W1 + ct * 4096 + kc * 512);
      #pragma unroll
      for (int rt = 0; rt < 4; ++rt)
        acc1[rt * 2 + ct] =
            __builtin_amdgcn_mfma_f32_16x16x32_bf16(a[rt], b, acc1[rt * 2 + ct], 0, 0, 0);
    }
    #pragma unroll
    for (int ct = 0; ct < 2; ++ct) {
      bf16x8 b = *(const bf16x8*)(W2 + ct * 4096 + kc * 512);
      #pragma unroll
      for (int rt = 0; rt < 4; ++rt)
        acc2[rt * 2 + ct] =
            __builtin_amdgcn_mfma_f32_16x16x32_bf16(a[rt], b, acc2[rt * 2 + ct], 0, 0, 0);
    }
  }
}

// ---------------- kernel 1: weight repack ----------------------------------
// dst element e = [m][nt][kc][lane][j]; value = src_m[k*256 + n],
// COLUMN REMAP: n = (nt>>1)*32 + (lane&15)*2 + (nt&1)
// -> fused wave w (ntiles 2w,2w+1): lane cols = w*32 + l16*2 + {0,1}
// -> cond wave w (ntiles 4w..4w+3): cols w*64 + (ct>>1)*32 + l16*2 + (ct&1)
__global__ void wprep_kernel(const float* __restrict__ condw,
                             const float* __restrict__ w1,
                             const float* __restrict__ skw,
                             const float* __restrict__ w2,
                             const float* __restrict__ bw1,
                             const float* __restrict__ bw2,
                             bf16_t* __restrict__ wts) {
  int e = blockIdx.x * 256 + threadIdx.x;
  int m = e >> 16;
  int r = e & 65535;
  int nt = r >> 12, kc = (r >> 9) & 7, lane = (r >> 3) & 63, j = r & 7;
  int n = (nt >> 1) * 32 + (lane & 15) * 2 + (nt & 1);
  int k = kc * 32 + (lane >> 4) * 8 + j;
  const float* src;
  if      (m == 0) src = condw;
  else if (m == 1) src = w1;                    // blk0_w1 rows 0..255 (cond part)
  else if (m == 2) src = skw;                   // blk0_skip_w rows 0..255
  else if (m == 3) src = w2;                    // blk0_w2
  else if (m <= 6) src = bw1 + (m - 4) * 65536; // blks_w1[i]
  else             src = bw2 + (m - 7) * 65536; // blks_w2[i]
  wts[e] = (bf16_t)src[k * 256 + n];
}

// ---------------- kernel 2: per-step vectors + scalars ---------------------
__global__ void prep_kernel(const float* __restrict__ time_w,
                            const float* __restrict__ time_b,
                            const float* __restrict__ w1,
                            const float* __restrict__ b1,
                            const float* __restrict__ skw,
                            const float* __restrict__ skb,
                            float* __restrict__ tvecs,
                            float* __restrict__ stepsc) {
  int s = blockIdx.x;          // 0..9, t = 90 - 10*s
  int j = threadIdx.x;         // 0..255
  int t = 90 - s * 10;
  float tval = (float)t;
  __shared__ float emb[256];
  __shared__ float temb[256];
  if (j < 128) {
    float freq = expf((float)j * -0.07252236513366287f);  // -ln(1e4)/127
    float e = tval * freq;
    emb[j] = sinf(e);
    emb[j + 128] = cosf(e);
  }
  __syncthreads();
  float a = time_b[j];
  for (int k = 0; k < 256; ++k) a = fmaf(emb[k], time_w[k * 256 + j], a);
  temb[j] = gelu_f(a);
  __syncthreads();
  float v1 = b1[j], v2 = skb[j];
  for (int k = 0; k < 256; ++k) {
    float tk = temb[k];
    v1 = fmaf(tk, w1[(256 + k) * 256 + j], v1);    // blk0_w1 rows 256..511
    v2 = fmaf(tk, skw[(256 + k) * 256 + j], v2);   // blk0_skip_w rows 256..511
  }
  tvecs[s * 512 + j] = v1;         // tw1 (includes b1)
  tvecs[s * 512 + 256 + j] = v2;   // tskip (includes skip_b)
  if (j == 0) {
    float step = (0.02f - 1e-4f) / 99.0f;
    float acp = 1.0f, beta = 0.0f;
    for (int i = 0; i <= t; ++i) {
      beta = fmaf((float)i, step, 1e-4f);
      acp *= (1.0f - beta);
    }
    stepsc[s * 4 + 0] = 1.0f / sqrtf(1.0f - beta);   // 1/sqrt(alpha)
    stepsc[s * 4 + 1] = beta / sqrtf(1.0f - acp);    // b/sqrt(1-acp)
    stepsc[s * 4 + 2] = (t > 0) ? sqrtf(beta) : 0.0f;
    stepsc[s * 4 + 3] = 0.0f;
  }
}

// ---------------- kernel 3: x0 + noises via PARTITIONABLE threefry ---------
__global__ void noise_kernel(float* __restrict__ xout, float* __restrict__ nout, int nb) {
  int gid = blockIdx.x * 256 + threadIdx.x;
  int nx = nb * 4;     // 131072 x0 elements
  int nn = nb * 40;    // 1310720 noise elements
  uint32_t k0, k1, o0, o1;
  if (gid < nx) {
    tf2(0u, 42u, 0u, 999u, k0, k1);                 // fold_in(key(42), 999)
    tf2(k0, k1, 0u, (uint32_t)gid, o0, o1);
    xout[gid] = nrm_from_bits(o0 ^ o1);
  } else if (gid < nx + nn) {
    int i = gid - nx;
    tf2(0u, 42u, 0u, 7u, k0, k1);                   // fold_in(key(42), 7)
    tf2(k0, k1, 0u, (uint32_t)i, o0, o1);
    nout[i] = nrm_from_bits(o0 ^ o1);
  }
}

// ---------------- kernel 4: cond = features @ cond_w + cond_b --------------
__global__ __launch_bounds__(256, 2) void cond_kernel(
    const float* __restrict__ feat, const bf16_t* __restrict__ wts,
    const float* __restrict__ condb, bf16_t* __restrict__ condg) {
  __shared__ __align__(16) bf16_t la[MTILE * KP];
  const int tid = threadIdx.x;
  const int wave = tid >> 6, lane = tid & 63, quad = lane >> 4, l16 = lane & 15;
  const int rowbase = blockIdx.x * MTILE;
  for (int it = 0; it < 16; ++it) {
    int e = (it * 256 + tid) * 4;
    int rr = e >> 8, c = e & 255;
    f32x4 v = *(const f32x4*)(feat + (size_t)(rowbase + rr) * 256 + c);
    bf16x4 bv;
    bv[0] = (bf16_t)v[0]; bv[1] = (bf16_t)v[1];
    bv[2] = (bf16_t)v[2]; bv[3] = (bf16_t)v[3];
    *(bf16x4*)(la + rr * KP + c) = bv;
  }
  __syncthreads();
  f32x4 acc[16];
  mm_tile(la + l16 * KP + quad * 8, wts + wave * 16384 + lane * 8, acc);
  const int c0 = wave * 64 + l16 * 2;            // ct 0,1 -> c0, ct 2,3 -> c0+32
  f32x2 b0 = *(const f32x2*)(condb + c0);
  f32x2 b1 = *(const f32x2*)(condb + c0 + 32);
  #pragma unroll
  for (int rt = 0; rt < 4; ++rt)
    #pragma unroll
    for (int r = 0; r < 4; ++r) {
      int row = rt * 16 + quad * 4 + r;
      bf16x2 p0, p1;
      p0[0] = (bf16_t)(acc[rt * 4 + 0][r] + b0[0]);
      p0[1] = (bf16_t)(acc[rt * 4 + 1][r] + b0[1]);
      p1[0] = (bf16_t)(acc[rt * 4 + 2][r] + b1[0]);
      p1[1] = (bf16_t)(acc[rt * 4 + 3][r] + b1[1]);
      *(bf16x2*)(condg + (size_t)(rowbase + row) * 256 + c0) = p0;
      *(bf16x2*)(condg + (size_t)(rowbase + row) * 256 + c0 + 32) = p1;
    }
}

// ---------------- kernel 5: fused 10-step sampler (512 thr / 8 waves) ------
__global__ __launch_bounds__(512, 1) void fused_kernel(
    const bf16_t* __restrict__ condg, const bf16_t* __restrict__ wts,
    const float* __restrict__ tvecs, const float* __restrict__ stepsc,
    const float* __restrict__ x0w, const float* __restrict__ noises,
    const float* __restrict__ w1bot, const float* __restrict__ skipbot,
    const float* __restrict__ b2v, const float* __restrict__ blksb1,
    const float* __restrict__ blksb2, const float* __restrict__ finalw,
    const float* __restrict__ finalb, float* __restrict__ out, int nb) {
  __shared__ __align__(16) bf16_t lcond[MTILE * KP];
  __shared__ __align__(16) bf16_t lact0[MTILE * KP];   // double-buffered act
  __shared__ __align__(16) bf16_t lact1[MTILE * KP];
  __shared__ __align__(16) float  lx[MTILE * 4];
  __shared__ __align__(16) float  lfw[1024];
  const int tid = threadIdx.x;
  const int wave = tid >> 6, lane = tid & 63, quad = lane >> 4, l16 = lane & 15;
  const int rowbase = blockIdx.x * MTILE;

  // stage cond tile (persists all 10 steps) + x0 + final_w
  {
    int rr = tid >> 3, c = (tid & 7) * 32;
    const bf16_t* src = condg + (size_t)(rowbase + rr) * 256 + c;
    bf16_t* dst = lcond + rr * KP + c;
    #pragma unroll
    for (int j = 0; j < 4; ++j)
      *(bf16x8*)(dst + j * 8) = *(const bf16x8*)(src + j * 8);
  }
  if (tid < 256) lx[tid] = x0w[rowbase * 4 + tid];
  lfw[tid] = finalw[tid];
  lfw[tid + 512] = finalw[tid + 512];
  __syncthreads();

  const bf16_t* Acond = lcond + l16 * KP + quad * 8;
  const bf16_t* A0    = lact0 + l16 * KP + quad * 8;
  const bf16_t* A1    = lact1 + l16 * KP + quad * 8;
  const int colw = wave * 32 + l16 * 2;          // 2 consecutive cols/lane
  const int wlane = wave * 8192 + lane * 8;
  f32x4 resid[8], work[8];

  // pack lane's 2 consecutive cols -> one ds_write_b32 per (rt,r)
  auto write_act = [&](bf16_t* dst) {
    #pragma unroll
    for (int rt = 0; rt < 4; ++rt)
      #pragma unroll
      for (int r = 0; r < 4; ++r) {
        bf16x2 pv;
        pv[0] = (bf16_t)work[rt * 2 + 0][r];
        pv[1] = (bf16_t)work[rt * 2 + 1][r];
        *(bf16x2*)(dst + (rt * 16 + quad * 4 + r) * KP + colw) = pv;
      }
  };
  // merged K=516-factorized epilogue: skip (resid, no gelu) + y1 (work, gelu)
  auto epi_bot_dual = [&](const float* tvsk, const float* botsk,
                          const float* tvw, const float* botw) {
    f32x2 tcs = *(const f32x2*)(tvsk + colw);
    f32x2 ss0 = *(const f32x2*)(botsk + colw);
    f32x2 ss1 = *(const f32x2*)(botsk + 256 + colw);
    f32x2 ss2 = *(const f32x2*)(botsk + 512 + colw);
    f32x2 ss3 = *(const f32x2*)(botsk + 768 + colw);
    f32x2 tcw = *(const f32x2*)(tvw + colw);
    f32x2 sw0 = *(const f32x2*)(botw + colw);
    f32x2 sw1 = *(const f32x2*)(botw + 256 + colw);
    f32x2 sw2 = *(const f32x2*)(botw + 512 + colw);
    f32x2 sw3 = *(const f32x2*)(botw + 768 + colw);
    #pragma unroll
    for (int rt = 0; rt < 4; ++rt)
      #pragma unroll
      for (int r = 0; r < 4; ++r) {
        f32x4 xv = *(const f32x4*)(lx + (rt * 16 + quad * 4 + r) * 4);
        f32x2 vs = f32x2{resid[rt * 2][r], resid[rt * 2 + 1][r]} + tcs;
        vs = fma2(bc2(xv[0]), ss0, vs);
        vs = fma2(bc2(xv[1]), ss1, vs);
        vs = fma2(bc2(xv[2]), ss2, vs);
        vs = fma2(bc2(xv[3]), ss3, vs);
        resid[rt * 2][r] = vs[0]; resid[rt * 2 + 1][r] = vs[1];
        f32x2 vw = f32x2{work[rt * 2][r], work[rt * 2 + 1][r]} + tcw;
        vw = fma2(bc2(xv[0]), sw0, vw);
        vw = fma2(bc2(xv[1]), sw1, vw);
        vw = fma2(bc2(xv[2]), sw2, vw);
        vw = fma2(bc2(xv[3]), sw3, vw);
        vw = gelu2(vw);
        work[rt * 2][r] = vw[0]; work[rt * 2 + 1][r] = vw[1];
      }
  };
  auto epi_gelu = [&](const float* bias) {
    f32x2 bcv = *(const f32x2*)(bias + colw);
    #pragma unroll
    for (int rt = 0; rt < 4; ++rt)
      #pragma unroll
      for (int r = 0; r < 4; ++r) {
        f32x2 v = f32x2{work[rt * 2][r], work[rt * 2 + 1][r]} + bcv;
        v = gelu2(v);
        work[rt * 2][r] = v[0]; work[rt * 2 + 1][r] = v[1];
      }
  };
  auto epi_gelu_res = [&](const float* bias) {
    f32x2 bcv = *(const f32x2*)(bias + colw);
    #pragma unroll
    for (int rt = 0; rt < 4; ++rt)
      #pragma unroll
      for (int r = 0; r < 4; ++r) {
        f32x2 v = gelu2(f32x2{work[rt * 2][r], work[rt * 2 + 1][r]} + bcv)
                + f32x2{resid[rt * 2][r], resid[rt * 2 + 1][r]};
        resid[rt * 2][r] = v[0]; resid[rt * 2 + 1][r] = v[1];
        work[rt * 2][r] = v[0];  work[rt * 2 + 1][r] = v[1];
      }
  };

  for (int s = 0; s < 10; ++s) {
    const float* tw  = tvecs + s * 512;
    const float* tsk = tvecs + s * 512 + 256;
    // skip -> resid, y1 -> work: ONE lcond pass, two B's, merged epilogue
    mm_tile2_dual(Acond, wts + 2 * 65536 + wlane, wts + 1 * 65536 + wlane,
                  resid, work);
    epi_bot_dual(tsk, skipbot, tw, w1bot);
    write_act(lact0);
    __syncthreads();                                   // B1: lact0 ready
    // h = gelu(y1 @ W2 + b2) + skip                   -> resid + lact1
    mm_tile2(A0, wts + 3 * 65536 + wlane, work);
    epi_gelu_res(b2v);
    write_act(lact1);          // different buffer than reads: no pre-barrier
    __syncthreads();                                   // B2: lact1 ready
    // 3 residual blocks; g1: lact1->lact0, g2: lact0->lact1
    for (int blk = 0; blk < 3; ++blk) {
      mm_tile2(A1, wts + (4 + blk) * 65536 + wlane, work);
      epi_gelu(blksb1 + blk * 256);
      write_act(lact0);
      __syncthreads();                                 // lact0 ready
      mm_tile2(A0, wts + (7 + blk) * 65536 + wlane, work);
      epi_gelu_res(blksb2 + blk * 256);
      write_act(lact1);
      __syncthreads();                                 // lact1 ready
    }
    // pred = h @ final_w + final_b; x-update (one thread per (row, action))
    if (tid < 256) {
      int prow = tid >> 2, pc = tid & 3;
      const bf16_t* hp = lact1 + prow * KP;
      float a0 = 0.f, a1 = 0.f, a2 = 0.f, a3 = 0.f;    // 4 chains: break dep
      #pragma unroll 2
      for (int k = 0; k < 256; k += 32) {
        #pragma unroll
        for (int q = 0; q < 4; ++q) {
          bf16x8 hv = *(const bf16x8*)(hp + k + q * 8);
          float* ap = (q == 0) ? &a0 : (q == 1) ? &a1 : (q == 2) ? &a2 : &a3;
          #pragma unroll
          for (int j = 0; j < 8; ++j)
            *ap = fmaf((float)hv[j], lfw[(k + q * 8 + j) * 4 + pc], *ap);
        }
      }
      float accp = finalb[pc] + ((a0 + a1) + (a2 + a3));
      f32x4 sc = *(const f32x4*)(stepsc + s * 4);
      float xv = lx[tid];
      xv = (xv - sc[1] * accp) * sc[0];
      xv = fmaf(sc[2], noises[(size_t)s * nb * 4 + rowbase * 4 + tid], xv);
      lx[tid] = xv;   // own slot; cross-thread reads only after barrier below
    }
    __syncthreads();                                   // B9: lx + lact1 done
  }
  if (tid < 256) {
    float xf = lx[tid];
    xf = fminf(1.0f, fmaxf(-1.0f, xf));
    out[rowbase * 4 + tid] = xf;
  }
}

// ---------------------------------------------------------------------------
extern "C" void kernel_launch(void* const* d_in, const int* in_sizes, int n_in,
                              void* d_out, int out_size, void* d_ws, size_t ws_size,
                              hipStream_t stream) {
  (void)n_in; (void)out_size; (void)ws_size;
  const float* features    = (const float*)d_in[0];
  const float* cond_w      = (const float*)d_in[1];
  const float* cond_b      = (const float*)d_in[2];
  const float* time_w      = (const float*)d_in[3];
  const float* time_b      = (const float*)d_in[4];
  const float* blk0_w1     = (const float*)d_in[5];
  const float* blk0_b1     = (const float*)d_in[6];
  const float* blk0_w2     = (const float*)d_in[7];
  const float* blk0_b2     = (const float*)d_in[8];
  const float* blk0_skip_w = (const float*)d_in[9];
  const float* blk0_skip_b = (const float*)d_in[10];
  const float* blks_w1     = (const float*)d_in[11];
  const float* blks_b1     = (const float*)d_in[12];
  const float* blks_w2     = (const float*)d_in[13];
  const float* blks_b2     = (const float*)d_in[14];
  const float* final_w     = (const float*)d_in[15];
  const float* final_b     = (const float*)d_in[16];

  const int nb = in_sizes[0] / 256;   // batch (32768)

  // workspace layout (bytes, 256-aligned)
  char* ws = (char*)d_ws;
  bf16_t* wts    = (bf16_t*)(ws + 0);        // 10 * 65536 bf16 = 1,310,720 B
  float*  tvecs  = (float*)(ws + 1310720);   // 10 * 512 f32    = 20,480 B
  float*  stepsc = (float*)(ws + 1331200);   // 10 * 4 f32      (pad to 256)
  float*  x0w    = (float*)(ws + 1331456);   // nb*4 f32        = 524,288 B
  float*  noisew = (float*)(ws + 1855744);   // 10*nb*4 f32     = 5,242,880 B
  bf16_t* condw  = (bf16_t*)(ws + 7098624);  // nb*256 bf16     = 16,777,216 B

  wprep_kernel<<<2560, 256, 0, stream>>>(cond_w, blk0_w1, blk0_skip_w, blk0_w2,
                                         blks_w1, blks_w2, wts);
  prep_kernel<<<10, 256, 0, stream>>>(time_w, time_b, blk0_w1, blk0_b1,
                                      blk0_skip_w, blk0_skip_b, tvecs, stepsc);
  noise_kernel<<<(nb * 44 + 255) / 256, 256, 0, stream>>>(x0w, noisew, nb);
  cond_kernel<<<nb / MTILE, 256, 0, stream>>>(features, wts, cond_b, condw);
  fused_kernel<<<nb / MTILE, 512, 0, stream>>>(
      condw, wts, tvecs, stepsc, x0w, noisew,
      blk0_w1 + 512 * 256, blk0_skip_w + 512 * 256, blk0_b2,
      blks_b1, blks_b2, final_w, final_b, (float*)d_out, nb);
}